// Round 5
// baseline (308.535 us; speedup 1.0000x reference)
//
#include <hip/hip_runtime.h>
#include <hip/hip_bf16.h>

#define V_NODES 100000
#define DIM 128
#define BATCH 16384
#define SAMP 64
#define NEDGE 640000
#define NSAMP (BATCH * SAMP)
#define NBKT 8
#define BKT_DIV 12500        // V_NODES / NBKT
#define SBLK 128             // score blocks per bucket

// bf16 helpers: raw-bit unpack (exact) and RNE pack
__device__ __forceinline__ float bl(unsigned u) { return __uint_as_float(u << 16); }
__device__ __forceinline__ float bh(unsigned u) { return __uint_as_float(u & 0xffff0000u); }
__device__ __forceinline__ unsigned short f2bf(float x) {
    unsigned u = __float_as_uint(x);
    return (unsigned short)((u + 0x7fffu + ((u >> 16) & 1u)) >> 16);
}

// ---------- K0: fp32 -> bf16 table conversion (emb_h) ----------
__global__ void k_cvt(const float* __restrict__ in, unsigned short* __restrict__ outh, int n4) {
    int i = blockIdx.x * blockDim.x + threadIdx.x;
    if (i < n4) {
        float4 v = ((const float4*)in)[i];
        ushort4 o;
        o.x = f2bf(v.x); o.y = f2bf(v.y); o.z = f2bf(v.z); o.w = f2bf(v.w);
        ((ushort4*)outh)[i] = o;
    }
}

// ---------- K1: count in-degrees (int atomics, 640K ops) ----------
__global__ void k_count(const int* __restrict__ dst, int* __restrict__ cnt, int E) {
    int e = blockIdx.x * blockDim.x + threadIdx.x;
    if (e < E) atomicAdd(&cnt[dst[e]], 1);
}

// ---------- K2a: per-1024-chunk sums ----------
__global__ void k_bsum(const int* __restrict__ cnt, int* __restrict__ bsum, int V) {
    __shared__ int red[4];
    int b = blockIdx.x, t = threadIdx.x;
    int s = 0;
    int base = b * 1024;
    for (int i = 0; i < 4; ++i) {
        int idx = base + i * 256 + t;
        if (idx < V) s += cnt[idx];
    }
    for (int m = 32; m >= 1; m >>= 1) s += __shfl_xor(s, m, 64);
    int lane = t & 63, wid = t >> 6;
    if (lane == 0) red[wid] = s;
    __syncthreads();
    if (t == 0) bsum[b] = red[0] + red[1] + red[2] + red[3];
}

// ---------- K2b: tiny serial scan of chunk sums ----------
__global__ void k_bscan(const int* __restrict__ bsum, int* __restrict__ boff, int nb) {
    if (threadIdx.x == 0 && blockIdx.x == 0) {
        int run = 0;
        for (int i = 0; i < nb; ++i) { boff[i] = run; run += bsum[i]; }
    }
}

// ---------- K2c: exclusive CSR offsets + dinv = 1/sqrt(deg+1) ----------
__global__ void k_offs(const int* __restrict__ cnt, const int* __restrict__ boff,
                       int* __restrict__ offs, float* __restrict__ dinv, int V) {
    __shared__ int wsum[4];
    int b = blockIdx.x, t = threadIdx.x;
    int lane = t & 63, wid = t >> 6;
    int base = b * 1024 + t * 4;
    int c[4];
    for (int j = 0; j < 4; ++j) {
        int idx = base + j;
        c[j] = (idx < V) ? cnt[idx] : 0;
    }
    int tot = c[0] + c[1] + c[2] + c[3];
    int x = tot;
    for (int off = 1; off < 64; off <<= 1) {
        int n = __shfl_up(x, off, 64);
        if (lane >= off) x += n;
    }
    int lex = x - tot;
    if (lane == 63) wsum[wid] = x;
    __syncthreads();
    int wpre = 0;
    for (int w = 0; w < wid; ++w) wpre += wsum[w];
    int o = boff[b] + wpre + lex;
    int pre = 0;
    for (int j = 0; j < 4; ++j) {
        int idx = base + j;
        if (idx < V) {
            offs[idx] = o + pre;
            dinv[idx] = 1.0f / sqrtf((float)(c[j] + 1));
        }
        pre += c[j];
    }
}

// ---------- K3: fill CSR (int atomic cursors) ----------
__global__ void k_fill(const int* __restrict__ src, const int* __restrict__ dst,
                       const int* __restrict__ offs, int* __restrict__ cursor,
                       int* __restrict__ csr, int E) {
    int e = blockIdx.x * blockDim.x + threadIdx.x;
    if (e < E) {
        int d = dst[e];
        int pos = atomicAdd(&cursor[d], 1);
        csr[offs[d] + pos] = src[e];
    }
}

// ---------- K4: aggregate in EMBEDDING space, bf16 gathers ----------
__global__ __launch_bounds__(256) void k_agg(const unsigned short* __restrict__ emb_h,
                     const int* __restrict__ offs, const int* __restrict__ cnt,
                     const int* __restrict__ csr, const float* __restrict__ dinv,
                     float* __restrict__ out, int V) {
    int wid = threadIdx.x >> 6;
    int lane = threadIdx.x & 63;
    int v = blockIdx.x * 4 + wid;
    if (v >= V) return;
    float dv = dinv[v];
    int beg = offs[v], num = cnt[v];
    int nid = 0; float nw = 0.0f;
    if (lane < num) {
        nid = csr[beg + lane];
        nw = dinv[nid];
    }
    unsigned u0 = ((const unsigned*)(emb_h + (size_t)v * DIM))[lane];
    float wself = dv * dv;
    float2 acc;
    acc.x = wself * bl(u0); acc.y = wself * bh(u0);
    int n0 = min(num, 64);
    for (int i = 0; i < n0; ++i) {
        int s = __shfl(nid, i, 64);
        float w = dv * __shfl(nw, i, 64);
        unsigned u = ((const unsigned*)(emb_h + (size_t)s * DIM))[lane];
        acc.x += w * bl(u); acc.y += w * bh(u);
    }
    for (int i = 64; i < num; ++i) {
        int s = csr[beg + i];
        float w = dv * dinv[s];
        unsigned u = ((const unsigned*)(emb_h + (size_t)s * DIM))[lane];
        acc.x += w * bl(u); acc.y += w * bh(u);
    }
    ((float2*)(out + (size_t)v * DIM))[lane] = acc;
}

// ---------- K5: in-place GEMM  nodes = nodes @ W + bias; also emit bf16 copy ----------
__global__ __launch_bounds__(256) void k_gemm(float* __restrict__ nodes,
                      unsigned short* __restrict__ nodes_h,
                      const float* __restrict__ W, const float* __restrict__ bias, int V) {
    __shared__ float rows[32][128];
    __shared__ float wld[32][128];
    int t = threadIdx.x;
    int rowbase = blockIdx.x * 32;
    {
        const float4* g = (const float4*)(nodes + (size_t)rowbase * DIM);
        float4* s = (float4*)&rows[0][0];
        #pragma unroll
        for (int i = 0; i < 4; ++i) s[t + i * 256] = g[t + i * 256];
    }
    int tr = t >> 5, tc = t & 31;
    float acc[4][4] = {{0.f}};
    for (int kt = 0; kt < 4; ++kt) {
        __syncthreads();
        {
            const float4* g = (const float4*)(W + kt * 32 * DIM);
            float4* s = (float4*)&wld[0][0];
            #pragma unroll
            for (int i = 0; i < 4; ++i) s[t + i * 256] = g[t + i * 256];
        }
        __syncthreads();
        #pragma unroll
        for (int k = 0; k < 32; ++k) {
            float4 wv = *(const float4*)&wld[k][tc * 4];
            float a0 = rows[tr * 4 + 0][kt * 32 + k];
            float a1 = rows[tr * 4 + 1][kt * 32 + k];
            float a2 = rows[tr * 4 + 2][kt * 32 + k];
            float a3 = rows[tr * 4 + 3][kt * 32 + k];
            acc[0][0] += a0 * wv.x; acc[0][1] += a0 * wv.y; acc[0][2] += a0 * wv.z; acc[0][3] += a0 * wv.w;
            acc[1][0] += a1 * wv.x; acc[1][1] += a1 * wv.y; acc[1][2] += a1 * wv.z; acc[1][3] += a1 * wv.w;
            acc[2][0] += a2 * wv.x; acc[2][1] += a2 * wv.y; acc[2][2] += a2 * wv.z; acc[2][3] += a2 * wv.w;
            acc[3][0] += a3 * wv.x; acc[3][1] += a3 * wv.y; acc[3][2] += a3 * wv.z; acc[3][3] += a3 * wv.w;
        }
    }
    float4 bv = *(const float4*)&bias[tc * 4];
    #pragma unroll
    for (int i = 0; i < 4; ++i) {
        int r = rowbase + tr * 4 + i;
        if (r < V) {
            float4 o;
            o.x = acc[i][0] + bv.x; o.y = acc[i][1] + bv.y;
            o.z = acc[i][2] + bv.z; o.w = acc[i][3] + bv.w;
            *(float4*)(nodes + (size_t)r * DIM + tc * 4) = o;
            ushort4 oh;
            oh.x = f2bf(o.x); oh.y = f2bf(o.y); oh.z = f2bf(o.z); oh.w = f2bf(o.w);
            *(ushort4*)(nodes_h + (size_t)r * DIM + tc * 4) = oh;
        }
    }
}

// ---------- K6a: compact item rows -> items_bf [B,128] bf16 (4 MB, L2-resident) ----------
__global__ __launch_bounds__(256) void k_items(const unsigned short* __restrict__ nodes_h,
        const int* __restrict__ items, unsigned short* __restrict__ items_bf) {
    int w = (blockIdx.x * blockDim.x + threadIdx.x) >> 6;
    int lane = threadIdx.x & 63;
    if (w >= BATCH) return;
    int id = items[w];
    unsigned v = ((const unsigned*)(nodes_h + (size_t)id * DIM))[lane];
    ((unsigned*)(items_bf + (size_t)w * DIM))[lane] = v;
}

// ---------- K6b: histogram samples into 8 node-id octile buckets ----------
__global__ void k_phist(const int* __restrict__ samples, int* __restrict__ pcnt, int n) {
    __shared__ int h[NBKT];
    int t = threadIdx.x;
    if (t < NBKT) h[t] = 0;
    __syncthreads();
    int i = blockIdx.x * blockDim.x + t;
    if (i < n) atomicAdd(&h[samples[i] / BKT_DIV], 1);
    __syncthreads();
    if (t < NBKT && h[t]) atomicAdd(&pcnt[t], h[t]);
}

// ---------- K6c: scan 8 bucket counts -> bases + fill cursors ----------
__global__ void k_pscan(const int* __restrict__ pcnt, int* __restrict__ pbase, int* __restrict__ pcur) {
    if (threadIdx.x == 0 && blockIdx.x == 0) {
        int run = 0;
        for (int i = 0; i < NBKT; ++i) { pbase[i] = run; pcur[i] = run; run += pcnt[i]; }
    }
}

// ---------- K6d: fill (id, dest) pairs, bucketed; block covers 2048 consecutive ----------
// samples (32 consecutive items) so each bucket chunk has L1-friendly item locality.
__global__ __launch_bounds__(256) void k_pfill(const int* __restrict__ samples,
        int* __restrict__ pcur, uint2* __restrict__ pairs, int n) {
    __shared__ int h[NBKT];
    __shared__ int gb[NBKT];
    int t = threadIdx.x;
    if (t < NBKT) h[t] = 0;
    __syncthreads();
    int base = blockIdx.x * 2048;
    int id8[8], loc8[8], bk8[8];
    #pragma unroll
    for (int j = 0; j < 8; ++j) {
        int i = base + j * 256 + t;
        if (i < n) {
            int id = samples[i];
            int b = id / BKT_DIV;
            id8[j] = id; bk8[j] = b;
            loc8[j] = atomicAdd(&h[b], 1);
        } else bk8[j] = -1;
    }
    __syncthreads();
    if (t < NBKT && h[t]) gb[t] = atomicAdd(&pcur[t], h[t]);
    __syncthreads();
    #pragma unroll
    for (int j = 0; j < 8; ++j) {
        if (bk8[j] >= 0) {
            int i = base + j * 256 + t;
            pairs[gb[bk8[j]] + loc8[j]] = make_uint2((unsigned)id8[j], (unsigned)i);
        }
    }
}

// ---------- K6e: bucketed scoring with XCD-affine dispatch ----------
// bucket = blockIdx.x % 8: default dispatch round-robins blocks over the 8 XCDs,
// so each XCD touches only its 3.2 MB node-row shard -> L2-resident gathers.
__global__ __launch_bounds__(256) void k_score2(const unsigned short* __restrict__ nodes_h,
        const unsigned short* __restrict__ items_bf, const uint2* __restrict__ pairs,
        const int* __restrict__ pcnt, const int* __restrict__ pbase,
        float* __restrict__ out) {
    int bkt = blockIdx.x & 7;
    int blk = blockIdx.x >> 3;
    int n = pcnt[bkt];
    int base = pbase[bkt];
    int t = threadIdx.x;
    int q = t & 3, grp = t >> 2;
    for (int e = blk * 64 + grp; e < n; e += SBLK * 64) {
        uint2 pr = pairs[base + e];
        int id = (int)pr.x, dest = (int)pr.y;
        const uint4* nrow = (const uint4*)(nodes_h + (size_t)id * DIM + q * 32);
        const uint4* irow = (const uint4*)(items_bf + (size_t)(dest >> 6) * DIM + q * 32);
        uint4 a[4], b[4];
        #pragma unroll
        for (int c = 0; c < 4; ++c) a[c] = nrow[c];
        #pragma unroll
        for (int c = 0; c < 4; ++c) b[c] = irow[c];
        float p = 0.f;
        #pragma unroll
        for (int c = 0; c < 4; ++c) {
            uint4 av = a[c], bv = b[c];
            p += bl(av.x) * bl(bv.x) + bh(av.x) * bh(bv.x);
            p += bl(av.y) * bl(bv.y) + bh(av.y) * bh(bv.y);
            p += bl(av.z) * bl(bv.z) + bh(av.z) * bh(bv.z);
            p += bl(av.w) * bl(bv.w) + bh(av.w) * bh(bv.w);
        }
        p += __shfl_xor(p, 1, 64);
        p += __shfl_xor(p, 2, 64);
        if (q == 0) out[dest] = p;
    }
}

extern "C" void kernel_launch(void* const* d_in, const int* in_sizes, int n_in,
                              void* d_out, int out_size, void* d_ws, size_t ws_size,
                              hipStream_t stream) {
    const int*   items   = (const int*)d_in[0];
    const int*   samples = (const int*)d_in[1];
    const int*   edges   = (const int*)d_in[2];
    const float* emb     = (const float*)d_in[3];
    const float* W       = (const float*)d_in[4];
    const float* bias    = (const float*)d_in[5];
    float* out = (float*)d_out;

    char* ws = (char*)d_ws;
    int*   cnt    = (int*)(ws + 0);                    // V ints (400 KB)
    int*   cursor = (int*)(ws + (512 << 10));          // V ints
    float* dinv   = (float*)(ws + (1 << 20));          // V floats
    int*   offs   = (int*)(ws + 3 * (512 << 10));      // V ints
    int*   bsum   = (int*)(ws + (2 << 20));            // ~98 ints
    int*   boff   = (int*)(ws + (2 << 20) + 4096);     // ~98 ints
    int*   pcnt   = (int*)(ws + (2 << 20) + 8192);     // 8 ints
    int*   pbase  = (int*)(ws + (2 << 20) + 8192 + 64);
    int*   pcur   = (int*)(ws + (2 << 20) + 8192 + 128);
    int*   csr    = (int*)(ws + (4 << 20));            // E ints (2.56 MB)
    unsigned short* emb_h   = (unsigned short*)(ws + (8 << 20));   // V*DIM bf16 (25.6 MB)
    unsigned short* nodes_h = emb_h;                   // alias: emb_h dead after k_agg
    float* nodes  = (float*)(ws + (34 << 20));         // V*DIM fp32 (ends 85.2 MB)
    // nodes fp32 is dead after k_gemm -> overlay pairs/items_bf on it:
    uint2* pairs = (uint2*)(ws + (34 << 20));                      // 1M uint2 (8 MB)
    unsigned short* items_bf = (unsigned short*)(ws + (44 << 20)); // B*DIM bf16 (4 MB)

    const int* esrc = edges;
    const int* edst = edges + NEDGE;

    hipMemsetAsync(ws, 0, (1 << 20), stream);   // zero cnt + cursor
    hipMemsetAsync(pcnt, 0, 64, stream);        // zero bucket counters

    int nb = (V_NODES + 1023) / 1024;
    int n4 = V_NODES * DIM / 4;
    k_cvt  <<<(n4 + 255) / 256, 256, 0, stream>>>(emb, emb_h, n4);
    k_count<<<(NEDGE + 255) / 256, 256, 0, stream>>>(edst, cnt, NEDGE);
    k_bsum <<<nb, 256, 0, stream>>>(cnt, bsum, V_NODES);
    k_bscan<<<1, 64, 0, stream>>>(bsum, boff, nb);
    k_offs <<<nb, 256, 0, stream>>>(cnt, boff, offs, dinv, V_NODES);
    k_fill <<<(NEDGE + 255) / 256, 256, 0, stream>>>(esrc, edst, offs, cursor, csr, NEDGE);
    k_agg  <<<(V_NODES + 3) / 4, 256, 0, stream>>>(emb_h, offs, cnt, csr, dinv, nodes, V_NODES);
    k_gemm <<<V_NODES / 32, 256, 0, stream>>>(nodes, nodes_h, W, bias, V_NODES);
    // ---- sample scoring path (nodes fp32 dead from here; region reused) ----
    k_items<<<BATCH / 4, 256, 0, stream>>>(nodes_h, items, items_bf);
    k_phist<<<(NSAMP + 255) / 256, 256, 0, stream>>>(samples, pcnt, NSAMP);
    k_pscan<<<1, 64, 0, stream>>>(pcnt, pbase, pcur);
    k_pfill<<<(NSAMP + 2047) / 2048, 256, 0, stream>>>(samples, pcur, pairs, NSAMP);
    k_score2<<<NBKT * SBLK, 256, 0, stream>>>(nodes_h, items_bf, pairs, pcnt, pbase, out);
}